// Round 12
// baseline (1323.550 us; speedup 1.0000x reference)
//
#include <hip/hip_runtime.h>

#define LEAKY(v) ((v) > 0.0f ? (v) : 0.01f * (v))
#define SCAN_BLK 1024
#define EPB 8192          // edges per block in bucket pipeline
#define BKN 256           // nodes per bucket

typedef __bf16 bf16x8 __attribute__((ext_vector_type(8)));
typedef float f32x4 __attribute__((ext_vector_type(4)));

// ---------------- bf16 helpers (RNE) ----------------
__device__ inline float bflo(unsigned int u) { return __uint_as_float(u << 16); }
__device__ inline float bfhi(unsigned int u) { return __uint_as_float(u & 0xFFFF0000u); }
__device__ inline unsigned int pack2bf(float lo, float hi) {
    unsigned int a = __float_as_uint(lo);
    unsigned int b = __float_as_uint(hi);
    a = (a + 0x7FFFu + ((a >> 16) & 1u)) >> 16;
    b = (b + 0x7FFFu + ((b >> 16) & 1u)) & 0xFFFF0000u;
    return a | b;
}
__device__ inline unsigned short f2bf(float f) {
    unsigned int u = __float_as_uint(f);
    return (unsigned short)((u + 0x7FFFu + ((u >> 16) & 1u)) >> 16);
}

// ---------------- fp8 e4m3 helpers (HW cvt, OCP on gfx950) ----------------
__device__ inline unsigned char f2f8(float v) {
    return (unsigned char)(__builtin_amdgcn_cvt_pk_fp8_f32(v, 0.0f, 0u, false) & 0xFFu);
}

// ================= bucket-sort CSR pipeline (no global atomics) =================

__global__ void histo_kernel(const int* __restrict__ src, const int* __restrict__ dst,
                             int* __restrict__ bh, int E, int NBK, int NBLK, int LEN) {
    extern __shared__ int lds[];           // 2*NBK ints
    int* hs = lds;
    int* hd = lds + NBK;
    for (int j = threadIdx.x; j < 2 * NBK; j += 512) lds[j] = 0;
    __syncthreads();
    int b = blockIdx.x;
    int e0 = b * EPB, e1 = min(e0 + EPB, E);
    for (int e = e0 + threadIdx.x; e < e1; e += 512) {
        atomicAdd(&hs[src[e] >> 8], 1);
        atomicAdd(&hd[dst[e] >> 8], 1);
    }
    __syncthreads();
    for (int j = threadIdx.x; j < NBK; j += 512) {
        bh[j * NBLK + b] = hs[j];
        bh[LEN + j * NBLK + b] = hd[j];
    }
}

__global__ void scan1_kernel(const int* __restrict__ deg, int* __restrict__ out,
                             int* __restrict__ bsums, int n) {
    __shared__ int sh[SCAN_BLK];
    int gid = blockIdx.x * SCAN_BLK + threadIdx.x;
    int v = (gid < n) ? deg[gid] : 0;
    sh[threadIdx.x] = v;
    __syncthreads();
    for (int off = 1; off < SCAN_BLK; off <<= 1) {
        int t = (threadIdx.x >= off) ? sh[threadIdx.x - off] : 0;
        __syncthreads();
        sh[threadIdx.x] += t;
        __syncthreads();
    }
    if (gid < n) out[gid + 1] = sh[threadIdx.x];
    if (threadIdx.x == SCAN_BLK - 1) bsums[blockIdx.x] = sh[threadIdx.x];
    if (gid == 0) out[0] = 0;
}

__global__ void scan2_kernel(int* __restrict__ bsums, int nb) {
    __shared__ int sh[SCAN_BLK];
    int v = (threadIdx.x < nb) ? bsums[threadIdx.x] : 0;
    sh[threadIdx.x] = v;
    __syncthreads();
    for (int off = 1; off < SCAN_BLK; off <<= 1) {
        int t = (threadIdx.x >= off) ? sh[threadIdx.x - off] : 0;
        __syncthreads();
        sh[threadIdx.x] += t;
        __syncthreads();
    }
    if (threadIdx.x < nb) bsums[threadIdx.x] = sh[threadIdx.x] - v;
}

__global__ void scan3_kernel(int* __restrict__ out, const int* __restrict__ bsums, int n) {
    int gid = blockIdx.x * SCAN_BLK + threadIdx.x;
    if (gid < n) out[gid + 1] += bsums[blockIdx.x];
}

__global__ void scat_kernel(const int* __restrict__ src, const int* __restrict__ dst,
                            const float* __restrict__ edata,
                            const float* __restrict__ mu, const float* __restrict__ sigma,
                            const int* __restrict__ bhs, unsigned char* __restrict__ srcb8,
                            int2* __restrict__ pay, int E, int NBK, int NBLK, int LEN) {
    extern __shared__ int cur[];           // 2*NBK ints
    int* cs = cur;
    int* cd = cur + NBK;
    int b = blockIdx.x;
    for (int j = threadIdx.x; j < NBK; j += 512) {
        cs[j] = bhs[j * NBLK + b];
        cd[j] = bhs[LEN + j * NBLK + b] - E;
    }
    __syncthreads();
    int e0 = b * EPB, e1 = min(e0 + EPB, E);
    for (int e = e0 + threadIdx.x; e < e1; e += 512) {
        int s = src[e];
        int d = dst[e];
        float ed = edata[e];
        float dd = ed - mu[0];
        float w = (ed == 1.0f) ? ed : expf(-(dd * dd) / sigma[0]);
        int ps = atomicAdd(&cs[s >> 8], 1);
        srcb8[ps] = (unsigned char)(s & 255);
        int pd = atomicAdd(&cd[d >> 8], 1);
        pay[pd] = make_int2(s | ((d & 255) << 24), __float_as_int(w));
    }
}

__global__ void ns_kernel(const unsigned char* __restrict__ srcb8, const int* __restrict__ bhs,
                          float* __restrict__ ns, int n, int NBLK) {
    __shared__ int cnt[BKN];
    int b = blockIdx.x;
    int j = threadIdx.x;
    cnt[j] = 0;
    __syncthreads();
    int base = bhs[b * NBLK];
    int endp = bhs[(b + 1) * NBLK];
    for (int e = base + j; e < endp; e += 256)
        atomicAdd(&cnt[srcb8[e]], 1);
    __syncthreads();
    int node = b * BKN + j;
    if (node < n) {
        int c = cnt[j];
        ns[node] = (c > 0) ? rsqrtf((float)c) : 0.0f;
    }
}

__global__ void csr_kernel(const int2* __restrict__ pay, const float* __restrict__ ns,
                           const int* __restrict__ bhs, int* __restrict__ rowptr,
                           float* __restrict__ nd, int2* __restrict__ es,
                           int n, int E, int NBK, int NBLK, int LEN) {
    __shared__ int cnt[BKN];
    __shared__ int cur[BKN];
    int b = blockIdx.x;
    int j = threadIdx.x;
    cnt[j] = 0;
    __syncthreads();
    int base = bhs[LEN + b * NBLK] - E;
    int endp = bhs[LEN + (b + 1) * NBLK] - E;
    for (int e = base + j; e < endp; e += 256)
        atomicAdd(&cnt[(pay[e].x >> 24) & 255], 1);
    __syncthreads();
    int c0 = cnt[j];
    for (int off = 1; off < 256; off <<= 1) {
        int t = (j >= off) ? cnt[j - off] : 0;
        __syncthreads();
        cnt[j] += t;
        __syncthreads();
    }
    int excl = cnt[j] - c0;
    cur[j] = base + excl;
    int node = b * BKN + j;
    if (node < n) {
        rowptr[node] = base + excl;
        nd[node] = (c0 > 0) ? rsqrtf((float)c0) : 0.0f;
    }
    if (b == NBK - 1 && j == 0) rowptr[n] = E;
    __syncthreads();
    for (int e = base + j; e < endp; e += 256) {
        int2 p = pay[e];
        int s = p.x & 0x00FFFFFF;
        float coef = ns[s] * __int_as_float(p.y);
        int pos = atomicAdd(&cur[(p.x >> 24) & 255], 1);
        es[pos] = make_int2(s, __float_as_int(coef));
    }
}

// ================= dense compute =================

__global__ void x2f8_kernel(const float* __restrict__ x, unsigned char* __restrict__ o8,
                            long long total4) {
    long long i = (long long)blockIdx.x * blockDim.x + threadIdx.x;
    if (i < total4) {
        float4 v = *reinterpret_cast<const float4*>(&x[i * 4]);
        unsigned int q = __builtin_amdgcn_cvt_pk_fp8_f32(v.x, v.y, 0u, false);
        q = __builtin_amdgcn_cvt_pk_fp8_f32(v.z, v.w, q, true);
        *reinterpret_cast<unsigned int*>(&o8[i * 4]) = q;
    }
}

__global__ void packW_kernel(const float* __restrict__ W, unsigned short* __restrict__ Wp,
                             int FI, int FO) {
    int KB = (FI + 31) / 32;
    int NB = FO / 16;
    int gid = blockIdx.x * blockDim.x + threadIdx.x;
    if (gid >= KB * NB * 64) return;
    int l = gid & 63;
    int tile = gid >> 6;
    int kb = tile % KB;
    int nb = tile / KB;
    int n = nb * 16 + (l & 15);
    int k0 = kb * 32 + (l >> 4) * 8;
    unsigned short tmp[8];
    #pragma unroll
    for (int j = 0; j < 8; ++j) {
        int k = k0 + j;
        tmp[j] = (k < FI) ? f2bf(W[(size_t)k * FO + n]) : (unsigned short)0;
    }
    *reinterpret_cast<uint4*>(&Wp[(size_t)gid * 8]) = *reinterpret_cast<uint4*>(tmp);
}

// ---------------- fp8 gather accumulate: 16 features/lane ----------------
#define F8ACC16(v, cc) { \
    auto q0 = __builtin_amdgcn_cvt_pk_f32_fp8((v).x, false); \
    auto q1 = __builtin_amdgcn_cvt_pk_f32_fp8((v).x, true);  \
    auto q2 = __builtin_amdgcn_cvt_pk_f32_fp8((v).y, false); \
    auto q3 = __builtin_amdgcn_cvt_pk_f32_fp8((v).y, true);  \
    auto q4 = __builtin_amdgcn_cvt_pk_f32_fp8((v).z, false); \
    auto q5 = __builtin_amdgcn_cvt_pk_f32_fp8((v).z, true);  \
    auto q6 = __builtin_amdgcn_cvt_pk_f32_fp8((v).w, false); \
    auto q7 = __builtin_amdgcn_cvt_pk_f32_fp8((v).w, true);  \
    a[0] = fmaf(q0[0], cc, a[0]);  a[1] = fmaf(q0[1], cc, a[1]); \
    a[2] = fmaf(q1[0], cc, a[2]);  a[3] = fmaf(q1[1], cc, a[3]); \
    a[4] = fmaf(q2[0], cc, a[4]);  a[5] = fmaf(q2[1], cc, a[5]); \
    a[6] = fmaf(q3[0], cc, a[6]);  a[7] = fmaf(q3[1], cc, a[7]); \
    a[8] = fmaf(q4[0], cc, a[8]);  a[9] = fmaf(q4[1], cc, a[9]); \
    a[10] = fmaf(q5[0], cc, a[10]); a[11] = fmaf(q5[1], cc, a[11]); \
    a[12] = fmaf(q6[0], cc, a[12]); a[13] = fmaf(q6[1], cc, a[13]); \
    a[14] = fmaf(q7[0], cc, a[14]); a[15] = fmaf(q7[1], cc, a[15]); }

// ---------------- fused A-layer: agg (into LDS) + MFMA mm + epilogue ----------------
// out = leaky((Agg(h8) @ W) * nd + b) -> bf16 (+ fp8 if W8)
template<int FI, int FO, int W8>
__global__ __launch_bounds__(256) void fused_a_kernel(
    const unsigned char* __restrict__ h8, const int* __restrict__ rowptr,
    const int2* __restrict__ es, const float* __restrict__ nd,
    const float* __restrict__ bias, const unsigned short* __restrict__ Wp,
    unsigned short* __restrict__ out16, unsigned char* __restrict__ out8, int n)
{
    constexpr int FIP = (FI + 31) / 32 * 32;
    constexpr int KB = FIP / 32;
    constexpr int NB = FO / 16;
    constexpr int LDA = FIP + 8;
    constexpr int JT = FI / 16;        // lanes per node in agg phase
    constexpr int NG = 256 / JT;       // nodes per pass
    __shared__ unsigned short As[64 * LDA];

    const int t = threadIdx.x;
    const int row0 = blockIdx.x * 64;

    // ---- Phase 1: aggregate 64 rows directly into the LDS A-tile (bf16) ----
    {
        const int g = t / JT;
        const int lane = t - g * JT;
        const int c = lane << 4;
        for (int base = 0; base < 64; base += NG) {
            int r = base + g;
            if (g < NG && r < 64) {
                float a[16] = {};
                int i = row0 + r;
                if (i < n) {
                    int beg = rowptr[i], end = rowptr[i + 1];
                    int e = beg;
                    for (; e + 4 <= end; e += 4) {
                        int2 e0 = es[e + 0], e1 = es[e + 1], e2 = es[e + 2], e3 = es[e + 3];
                        uint4 v0 = *reinterpret_cast<const uint4*>(&h8[(size_t)e0.x * FI + c]);
                        uint4 v1 = *reinterpret_cast<const uint4*>(&h8[(size_t)e1.x * FI + c]);
                        uint4 v2 = *reinterpret_cast<const uint4*>(&h8[(size_t)e2.x * FI + c]);
                        uint4 v3 = *reinterpret_cast<const uint4*>(&h8[(size_t)e3.x * FI + c]);
                        float c0 = __int_as_float(e0.y), c1 = __int_as_float(e1.y);
                        float c2 = __int_as_float(e2.y), c3 = __int_as_float(e3.y);
                        F8ACC16(v0, c0)
                        F8ACC16(v1, c1)
                        F8ACC16(v2, c2)
                        F8ACC16(v3, c3)
                    }
                    for (; e < end; ++e) {
                        int2 e0 = es[e];
                        uint4 v0 = *reinterpret_cast<const uint4*>(&h8[(size_t)e0.x * FI + c]);
                        float c0 = __int_as_float(e0.y);
                        F8ACC16(v0, c0)
                    }
                }
                uint4 p0, p1;
                p0.x = pack2bf(a[0], a[1]);   p0.y = pack2bf(a[2], a[3]);
                p0.z = pack2bf(a[4], a[5]);   p0.w = pack2bf(a[6], a[7]);
                p1.x = pack2bf(a[8], a[9]);   p1.y = pack2bf(a[10], a[11]);
                p1.z = pack2bf(a[12], a[13]); p1.w = pack2bf(a[14], a[15]);
                *reinterpret_cast<uint4*>(&As[r * LDA + c]) = p0;
                *reinterpret_cast<uint4*>(&As[r * LDA + c + 8]) = p1;
            }
        }
    }
    // zero the K-tail (Wp has zero B there, but LDS garbage could be Inf/NaN)
    if constexpr (FIP > FI) {
        constexpr int TAIL = FIP - FI;
        for (int idx = t; idx < 64 * TAIL; idx += 256) {
            int r = idx / TAIL;
            int k = FI + (idx - r * TAIL);
            As[r * LDA + k] = 0;
        }
    }
    __syncthreads();

    // ---- Phase 2: MFMA mm + fused epilogue ----
    const int w = t >> 6;
    const int l = t & 63;
    const int arow = (w << 4) + (l & 15);
    const int koff = (l >> 4) << 3;

    bf16x8 a[KB];
    #pragma unroll
    for (int kb = 0; kb < KB; ++kb)
        a[kb] = *reinterpret_cast<const bf16x8*>(&As[arow * LDA + kb * 32 + koff]);

    f32x4 acc[NB] = {};
    #pragma unroll
    for (int nb = 0; nb < NB; ++nb) {
        #pragma unroll
        for (int kb = 0; kb < KB; ++kb) {
            bf16x8 b = *reinterpret_cast<const bf16x8*>(&Wp[(size_t)((nb * KB + kb) * 64 + l) * 8]);
            acc[nb] = __builtin_amdgcn_mfma_f32_16x16x32_bf16(a[kb], b, acc[nb], 0, 0, 0);
        }
    }

    const int col = l & 15;
    const int rb = (l >> 4) << 2;
    #pragma unroll
    for (int r = 0; r < 4; ++r) {
        int grow = row0 + (w << 4) + rb + r;
        if (grow < n) {
            float s = nd[grow];
            #pragma unroll
            for (int nb = 0; nb < NB; ++nb) {
                float v = acc[nb][r];
                v = v * s + bias[nb * 16 + col];
                v = LEAKY(v);
                out16[(size_t)grow * FO + nb * 16 + col] = f2bf(v);
                if (W8)
                    out8[(size_t)grow * FO + nb * 16 + col] = f2f8(v);
            }
        }
    }
}

// ---------------- standalone agg (order-B epilogue): fp8 gather -> bf16+fp8 ----------------
__global__ void agg_kernel(const unsigned char* __restrict__ h8,
                           const int* __restrict__ rowptr, const int2* __restrict__ es,
                           const float* __restrict__ nd, const float* __restrict__ bias,
                           unsigned short* __restrict__ out16, unsigned char* __restrict__ out8,
                           int n, int jt, int ng) {
    int g = threadIdx.x / jt;
    if (g >= ng) return;
    int i = blockIdx.x * ng + g;
    if (i >= n) return;
    int c = (threadIdx.x - g * jt) << 4;   // feature offset (16 per lane)
    int F = jt << 4;
    int beg = rowptr[i], end = rowptr[i + 1];
    float a[16] = {};
    int e = beg;
    for (; e + 4 <= end; e += 4) {
        int2 e0 = es[e + 0], e1 = es[e + 1], e2 = es[e + 2], e3 = es[e + 3];
        uint4 v0 = *reinterpret_cast<const uint4*>(&h8[(size_t)e0.x * F + c]);
        uint4 v1 = *reinterpret_cast<const uint4*>(&h8[(size_t)e1.x * F + c]);
        uint4 v2 = *reinterpret_cast<const uint4*>(&h8[(size_t)e2.x * F + c]);
        uint4 v3 = *reinterpret_cast<const uint4*>(&h8[(size_t)e3.x * F + c]);
        float c0 = __int_as_float(e0.y), c1 = __int_as_float(e1.y);
        float c2 = __int_as_float(e2.y), c3 = __int_as_float(e3.y);
        F8ACC16(v0, c0)
        F8ACC16(v1, c1)
        F8ACC16(v2, c2)
        F8ACC16(v3, c3)
    }
    for (; e < end; ++e) {
        int2 e0 = es[e];
        uint4 v0 = *reinterpret_cast<const uint4*>(&h8[(size_t)e0.x * F + c]);
        float c0 = __int_as_float(e0.y);
        F8ACC16(v0, c0)
    }
    float s = nd[i];
    #pragma unroll
    for (int j = 0; j < 16; ++j) {
        float v = a[j] * s + bias[c + j];
        a[j] = LEAKY(v);
    }
    uint4 p0, p1;
    p0.x = pack2bf(a[0], a[1]);   p0.y = pack2bf(a[2], a[3]);
    p0.z = pack2bf(a[4], a[5]);   p0.w = pack2bf(a[6], a[7]);
    p1.x = pack2bf(a[8], a[9]);   p1.y = pack2bf(a[10], a[11]);
    p1.z = pack2bf(a[12], a[13]); p1.w = pack2bf(a[14], a[15]);
    *reinterpret_cast<uint4*>(&out16[(size_t)i * F + c]) = p0;
    *reinterpret_cast<uint4*>(&out16[(size_t)i * F + c + 8]) = p1;
    uint4 q;
    q.x = __builtin_amdgcn_cvt_pk_fp8_f32(a[0], a[1], 0u, false);
    q.x = __builtin_amdgcn_cvt_pk_fp8_f32(a[2], a[3], q.x, true);
    q.y = __builtin_amdgcn_cvt_pk_fp8_f32(a[4], a[5], 0u, false);
    q.y = __builtin_amdgcn_cvt_pk_fp8_f32(a[6], a[7], q.y, true);
    q.z = __builtin_amdgcn_cvt_pk_fp8_f32(a[8], a[9], 0u, false);
    q.z = __builtin_amdgcn_cvt_pk_fp8_f32(a[10], a[11], q.z, true);
    q.w = __builtin_amdgcn_cvt_pk_fp8_f32(a[12], a[13], 0u, false);
    q.w = __builtin_amdgcn_cvt_pk_fp8_f32(a[14], a[15], q.w, true);
    *reinterpret_cast<uint4*>(&out8[(size_t)i * F + c]) = q;
}

// ---------------- MFMA matmul (order-B pre-agg): out8 = fp8(A @ W) ----------------
template<int FI, int FO>
__global__ __launch_bounds__(256) void mm_mfma_kernel(
    const unsigned short* __restrict__ Ab, const unsigned short* __restrict__ Wp,
    unsigned char* __restrict__ out8, int n)
{
    constexpr int FIP = (FI + 31) / 32 * 32;
    constexpr int KB = FIP / 32;
    constexpr int NB = FO / 16;
    constexpr int LDA = FIP + 8;
    constexpr int RW = FIP / 8;
    __shared__ unsigned short As[64 * LDA];

    const int t = threadIdx.x;
    const int row0 = blockIdx.x * 64;

    for (int idx = t; idx < 64 * RW; idx += 256) {
        int r = idx / RW;
        int c8 = (idx - r * RW) * 8;
        int grow = row0 + r;
        uint4 v = make_uint4(0u, 0u, 0u, 0u);
        if (grow < n && c8 < FI)
            v = *reinterpret_cast<const uint4*>(&Ab[(size_t)grow * FI + c8]);
        *reinterpret_cast<uint4*>(&As[r * LDA + c8]) = v;
    }
    __syncthreads();

    const int w = t >> 6;
    const int l = t & 63;
    const int arow = (w << 4) + (l & 15);
    const int koff = (l >> 4) << 3;

    bf16x8 a[KB];
    #pragma unroll
    for (int kb = 0; kb < KB; ++kb)
        a[kb] = *reinterpret_cast<const bf16x8*>(&As[arow * LDA + kb * 32 + koff]);

    f32x4 acc[NB] = {};
    #pragma unroll
    for (int nb = 0; nb < NB; ++nb) {
        #pragma unroll
        for (int kb = 0; kb < KB; ++kb) {
            bf16x8 b = *reinterpret_cast<const bf16x8*>(&Wp[(size_t)((nb * KB + kb) * 64 + l) * 8]);
            acc[nb] = __builtin_amdgcn_mfma_f32_16x16x32_bf16(a[kb], b, acc[nb], 0, 0, 0);
        }
    }

    const int col = l & 15;
    const int rb = (l >> 4) << 2;
    #pragma unroll
    for (int r = 0; r < 4; ++r) {
        int grow = row0 + (w << 4) + rb + r;
        if (grow < n) {
            #pragma unroll
            for (int nb = 0; nb < NB; ++nb)
                out8[(size_t)grow * FO + nb * 16 + col] = f2f8(acc[nb][r]);
        }
    }
}

// ---------------- mean over nodes (bf16 in, F=160) ----------------
__global__ __launch_bounds__(320) void mean_kernel(const unsigned short* __restrict__ h,
                                                   float* __restrict__ acc, int n) {
    __shared__ float lacc[160];
    int t = threadIdx.x;
    for (int j = t; j < 160; j += 320) lacc[j] = 0.0f;
    __syncthreads();
    int lane = t % 20;
    int rg = t / 20;
    float a0 = 0, a1 = 0, a2 = 0, a3 = 0, a4 = 0, a5 = 0, a6 = 0, a7 = 0;
    for (int i = blockIdx.x * 16 + rg; i < n; i += gridDim.x * 16) {
        uint4 v = *reinterpret_cast<const uint4*>(&h[(size_t)i * 160 + lane * 8]);
        a0 += bflo(v.x); a1 += bfhi(v.x);
        a2 += bflo(v.y); a3 += bfhi(v.y);
        a4 += bflo(v.z); a5 += bfhi(v.z);
        a6 += bflo(v.w); a7 += bfhi(v.w);
    }
    int c = lane * 8;
    atomicAdd(&lacc[c + 0], a0); atomicAdd(&lacc[c + 1], a1);
    atomicAdd(&lacc[c + 2], a2); atomicAdd(&lacc[c + 3], a3);
    atomicAdd(&lacc[c + 4], a4); atomicAdd(&lacc[c + 5], a5);
    atomicAdd(&lacc[c + 6], a6); atomicAdd(&lacc[c + 7], a7);
    __syncthreads();
    for (int j = t; j < 160; j += 320) atomicAdd(&acc[j], lacc[j]);
}

// ---------------- head ----------------
__global__ void head_kernel(const float* __restrict__ acc, const float* __restrict__ Wd1,
                            const float* __restrict__ bd1, const float* __restrict__ Wd2,
                            const float* __restrict__ bd2, float* __restrict__ out, int n) {
    __shared__ float gm[160];
    __shared__ float h1[140];
    int tid = threadIdx.x;
    if (tid < 160) {
        float v = acc[tid] / (float)n;
        gm[tid] = LEAKY(v);
    }
    __syncthreads();
    if (tid < 140) {
        float s = bd1[tid];
        for (int k = 0; k < 160; ++k) s += gm[k] * Wd1[k * 140 + tid];
        h1[tid] = LEAKY(s);
    }
    __syncthreads();
    if (tid < 2) {
        float s = bd2[tid];
        for (int k = 0; k < 140; ++k) s += h1[k] * Wd2[k * 2 + tid];
        out[tid] = 1.0f / (1.0f + expf(-s));
    }
}

extern "C" void kernel_launch(void* const* d_in, const int* in_sizes, int n_in,
                              void* d_out, int out_size, void* d_ws, size_t ws_size,
                              hipStream_t stream) {
    static const int dims[12] = {64, 80, 160, 112, 160, 176, 96, 144, 96, 128, 96, 160};

    const float* x     = (const float*)d_in[0];
    const int*   src   = (const int*)d_in[1];
    const int*   dst   = (const int*)d_in[2];
    const float* edata = (const float*)d_in[3];
    const float* W[11];
    const float* B[11];
    for (int i = 0; i < 11; ++i) {
        W[i] = (const float*)d_in[4 + 2 * i];
        B[i] = (const float*)d_in[5 + 2 * i];
    }
    const float* Wd1   = (const float*)d_in[26];
    const float* bd1   = (const float*)d_in[27];
    const float* Wd2   = (const float*)d_in[28];
    const float* bd2   = (const float*)d_in[29];
    const float* mu    = (const float*)d_in[30];
    const float* sigma = (const float*)d_in[31];
    float* out = (float*)d_out;

    const int N = in_sizes[0] / 64;
    const int E = in_sizes[1];
    const int FMAX = 176;

    const int NBK  = (N + BKN - 1) / BKN;
    const int NBLK = (E + EPB - 1) / EPB;
    const int LEN  = NBK * NBLK;

    size_t woff[11];
    size_t wtot = 0;
    for (int l = 0; l < 11; ++l) {
        woff[l] = wtot;
        int fip = (dims[l] + 31) / 32 * 32;
        wtot += (size_t)fip * dims[l + 1];
    }

    char* wsb = (char*)d_ws;
    size_t o = 0;
    auto alloc = [&](size_t bytes) { void* p = wsb + o; o += (bytes + 255) & ~(size_t)255; return p; };
    unsigned short* hb_main = (unsigned short*)alloc((size_t)N * FMAX * 2);
    unsigned char*  h8_main = (unsigned char*) alloc((size_t)N * FMAX);
    unsigned char*  h8_t    = (unsigned char*) alloc((size_t)N * FMAX);
    unsigned short* Wp  = (unsigned short*)alloc(wtot * 2);
    int2*  es      = (int2*) alloc((size_t)E * sizeof(int2));
    int2*  pay     = (int2*) alloc((size_t)E * sizeof(int2));
    unsigned char* srcb8 = (unsigned char*)alloc((size_t)E);
    int*   bh      = (int*)  alloc((size_t)(2 * LEN) * sizeof(int));
    int*   bhs     = (int*)  alloc((size_t)(2 * LEN + 1) * sizeof(int));
    int*   rowptr  = (int*)  alloc((size_t)(N + 1) * sizeof(int));
    float* ns      = (float*)alloc((size_t)N * sizeof(float));
    float* nd      = (float*)alloc((size_t)N * sizeof(float));
    int*   bsums   = (int*)  alloc(2048 * sizeof(int));
    float* acc     = (float*)alloc(160 * sizeof(float));

    // ---- bucket-sort CSR pipeline ----
    histo_kernel<<<NBLK, 512, 2 * NBK * sizeof(int), stream>>>(src, dst, bh, E, NBK, NBLK, LEN);
    int snb = (2 * LEN + SCAN_BLK - 1) / SCAN_BLK;
    scan1_kernel<<<snb, SCAN_BLK, 0, stream>>>(bh, bhs, bsums, 2 * LEN);
    scan2_kernel<<<1, SCAN_BLK, 0, stream>>>(bsums, snb);
    scan3_kernel<<<snb, SCAN_BLK, 0, stream>>>(bhs, bsums, 2 * LEN);
    scat_kernel<<<NBLK, 512, 2 * NBK * sizeof(int), stream>>>(src, dst, edata, mu, sigma,
                                                              bhs, srcb8, pay, E, NBK, NBLK, LEN);
    ns_kernel<<<NBK, 256, 0, stream>>>(srcb8, bhs, ns, N, NBLK);
    csr_kernel<<<NBK, 256, 0, stream>>>(pay, ns, bhs, rowptr, nd, es, N, E, NBK, NBLK, LEN);

    // ---- x -> fp8 ; W -> packed bf16 fragments ----
    long long x4 = (long long)N * 64 / 4;
    x2f8_kernel<<<(int)((x4 + 255) / 256), 256, 0, stream>>>(x, h8_main, x4);
    for (int l = 0; l < 11; ++l) {
        int fip = (dims[l] + 31) / 32 * 32;
        int threads = (fip / 32) * (dims[l + 1] / 16) * 64;
        packW_kernel<<<(threads + 255) / 256, 256, 0, stream>>>(W[l], Wp + woff[l],
                                                                dims[l], dims[l + 1]);
    }

    // ---- 11 GCN layers ----
    const int mmgrid = (N + 63) / 64;

    // order A (FO >= FI): fused agg+mm; W8 = write fp8 iff next layer is order A
    #define DO_A(FI, FO, l, W8) { \
        fused_a_kernel<FI, FO, W8><<<mmgrid, 256, 0, stream>>>( \
            h8_main, rowptr, es, nd, B[l], Wp + woff[l], hb_main, h8_main, N); }

    // order B (FO < FI): mm plain -> h8_t (fp8); agg with fused epilogue
    #define DO_B(FI, FO, l) { \
        mm_mfma_kernel<FI, FO><<<mmgrid, 256, 0, stream>>>( \
            hb_main, Wp + woff[l], h8_t, N); \
        constexpr int jt = FO / 16; constexpr int ng = 256 / jt; \
        agg_kernel<<<(N + ng - 1) / ng, 256, 0, stream>>>( \
            h8_t, rowptr, es, nd, B[l], hb_main, h8_main, N, jt, ng); }

    DO_A(64, 80, 0, 1)      // next L1 is A: write fp8
    DO_A(80, 160, 1, 0)     // next L2 is B: bf16 only
    DO_B(160, 112, 2)
    DO_A(112, 160, 3, 1)    // next L4 is A
    DO_A(160, 176, 4, 0)    // next L5 is B
    DO_B(176, 96, 5)
    DO_A(96, 144, 6, 0)     // next L7 is B
    DO_B(144, 96, 7)
    DO_A(96, 128, 8, 0)     // next L9 is B
    DO_B(128, 96, 9)
    DO_A(96, 160, 10, 0)    // next is mean: bf16 only

    #undef DO_A
    #undef DO_B

    // ---- mean over nodes -> head ----
    hipMemsetAsync(acc, 0, 160 * sizeof(float), stream);
    mean_kernel<<<256, 320, 0, stream>>>(hb_main, acc, N);
    head_kernel<<<1, 256, 0, stream>>>(acc, Wd1, bd1, Wd2, bd2, out, N);
}

// Round 13
// 1277.158 us; speedup vs baseline: 1.0363x; 1.0363x over previous
//
#include <hip/hip_runtime.h>

#define LEAKY(v) ((v) > 0.0f ? (v) : 0.01f * (v))
#define SCAN_BLK 1024
#define EPB 16384         // edges per block in bucket pipeline
#define BKN 256           // nodes per bucket

typedef __bf16 bf16x8 __attribute__((ext_vector_type(8)));
typedef float f32x4 __attribute__((ext_vector_type(4)));

// ---------------- bf16 helpers (RNE) ----------------
__device__ inline float bflo(unsigned int u) { return __uint_as_float(u << 16); }
__device__ inline float bfhi(unsigned int u) { return __uint_as_float(u & 0xFFFF0000u); }
__device__ inline unsigned int pack2bf(float lo, float hi) {
    unsigned int a = __float_as_uint(lo);
    unsigned int b = __float_as_uint(hi);
    a = (a + 0x7FFFu + ((a >> 16) & 1u)) >> 16;
    b = (b + 0x7FFFu + ((b >> 16) & 1u)) & 0xFFFF0000u;
    return a | b;
}
__device__ inline unsigned short f2bf(float f) {
    unsigned int u = __float_as_uint(f);
    return (unsigned short)((u + 0x7FFFu + ((u >> 16) & 1u)) >> 16);
}

// ---------------- fp8 e4m3 helpers (HW cvt, OCP on gfx950) ----------------
__device__ inline unsigned char f2f8(float v) {
    return (unsigned char)(__builtin_amdgcn_cvt_pk_fp8_f32(v, 0.0f, 0u, false) & 0xFFu);
}

// ================= bucket-sort CSR pipeline (no global atomics) =================

__global__ void histo_kernel(const int* __restrict__ src, const int* __restrict__ dst,
                             int* __restrict__ bh, int E, int NBK, int NBLK, int LEN) {
    extern __shared__ int lds[];           // 2*NBK ints
    int* hs = lds;
    int* hd = lds + NBK;
    for (int j = threadIdx.x; j < 2 * NBK; j += 512) lds[j] = 0;
    __syncthreads();
    int b = blockIdx.x;
    int e0 = b * EPB, e1 = min(e0 + EPB, E);
    for (int e = e0 + threadIdx.x; e < e1; e += 512) {
        atomicAdd(&hs[src[e] >> 8], 1);
        atomicAdd(&hd[dst[e] >> 8], 1);
    }
    __syncthreads();
    for (int j = threadIdx.x; j < NBK; j += 512) {
        bh[j * NBLK + b] = hs[j];
        bh[LEN + j * NBLK + b] = hd[j];
    }
}

__global__ void scan1_kernel(const int* __restrict__ deg, int* __restrict__ out,
                             int* __restrict__ bsums, int n) {
    __shared__ int sh[SCAN_BLK];
    int gid = blockIdx.x * SCAN_BLK + threadIdx.x;
    int v = (gid < n) ? deg[gid] : 0;
    sh[threadIdx.x] = v;
    __syncthreads();
    for (int off = 1; off < SCAN_BLK; off <<= 1) {
        int t = (threadIdx.x >= off) ? sh[threadIdx.x - off] : 0;
        __syncthreads();
        sh[threadIdx.x] += t;
        __syncthreads();
    }
    if (gid < n) out[gid + 1] = sh[threadIdx.x];
    if (threadIdx.x == SCAN_BLK - 1) bsums[blockIdx.x] = sh[threadIdx.x];
    if (gid == 0) out[0] = 0;
}

__global__ void scan2_kernel(int* __restrict__ bsums, int nb) {
    __shared__ int sh[SCAN_BLK];
    int v = (threadIdx.x < nb) ? bsums[threadIdx.x] : 0;
    sh[threadIdx.x] = v;
    __syncthreads();
    for (int off = 1; off < SCAN_BLK; off <<= 1) {
        int t = (threadIdx.x >= off) ? sh[threadIdx.x - off] : 0;
        __syncthreads();
        sh[threadIdx.x] += t;
        __syncthreads();
    }
    if (threadIdx.x < nb) bsums[threadIdx.x] = sh[threadIdx.x] - v;
}

__global__ void scan3_kernel(int* __restrict__ out, const int* __restrict__ bsums, int n) {
    int gid = blockIdx.x * SCAN_BLK + threadIdx.x;
    if (gid < n) out[gid + 1] += bsums[blockIdx.x];
}

__global__ void scat_kernel(const int* __restrict__ src, const int* __restrict__ dst,
                            const float* __restrict__ edata,
                            const float* __restrict__ mu, const float* __restrict__ sigma,
                            const int* __restrict__ bhs, unsigned char* __restrict__ srcb8,
                            int2* __restrict__ pay, int E, int NBK, int NBLK, int LEN) {
    extern __shared__ int cur[];           // 2*NBK ints
    int* cs = cur;
    int* cd = cur + NBK;
    int b = blockIdx.x;
    for (int j = threadIdx.x; j < NBK; j += 512) {
        cs[j] = bhs[j * NBLK + b];
        cd[j] = bhs[LEN + j * NBLK + b] - E;
    }
    __syncthreads();
    int e0 = b * EPB, e1 = min(e0 + EPB, E);
    for (int e = e0 + threadIdx.x; e < e1; e += 512) {
        int s = src[e];
        int d = dst[e];
        float ed = edata[e];
        float dd = ed - mu[0];
        float w = (ed == 1.0f) ? ed : expf(-(dd * dd) / sigma[0]);
        int ps = atomicAdd(&cs[s >> 8], 1);
        srcb8[ps] = (unsigned char)(s & 255);
        int pd = atomicAdd(&cd[d >> 8], 1);
        pay[pd] = make_int2(s | ((d & 255) << 24), __float_as_int(w));
    }
}

__global__ void ns_kernel(const unsigned char* __restrict__ srcb8, const int* __restrict__ bhs,
                          float* __restrict__ ns, int n, int NBLK) {
    __shared__ int cnt[BKN];
    int b = blockIdx.x;
    int j = threadIdx.x;
    cnt[j] = 0;
    __syncthreads();
    int base = bhs[b * NBLK];
    int endp = bhs[(b + 1) * NBLK];
    for (int e = base + j; e < endp; e += 256)
        atomicAdd(&cnt[srcb8[e]], 1);
    __syncthreads();
    int node = b * BKN + j;
    if (node < n) {
        int c = cnt[j];
        ns[node] = (c > 0) ? rsqrtf((float)c) : 0.0f;
    }
}

__global__ void csr_kernel(const int2* __restrict__ pay, const float* __restrict__ ns,
                           const int* __restrict__ bhs, int* __restrict__ rowptr,
                           float* __restrict__ nd, int2* __restrict__ es,
                           int n, int E, int NBK, int NBLK, int LEN) {
    __shared__ int cnt[BKN];
    __shared__ int cur[BKN];
    int b = blockIdx.x;
    int j = threadIdx.x;
    cnt[j] = 0;
    __syncthreads();
    int base = bhs[LEN + b * NBLK] - E;
    int endp = bhs[LEN + (b + 1) * NBLK] - E;
    for (int e = base + j; e < endp; e += 256)
        atomicAdd(&cnt[(pay[e].x >> 24) & 255], 1);
    __syncthreads();
    int c0 = cnt[j];
    for (int off = 1; off < 256; off <<= 1) {
        int t = (j >= off) ? cnt[j - off] : 0;
        __syncthreads();
        cnt[j] += t;
        __syncthreads();
    }
    int excl = cnt[j] - c0;
    cur[j] = base + excl;
    int node = b * BKN + j;
    if (node < n) {
        rowptr[node] = base + excl;
        nd[node] = (c0 > 0) ? rsqrtf((float)c0) : 0.0f;
    }
    if (b == NBK - 1 && j == 0) rowptr[n] = E;
    __syncthreads();
    for (int e = base + j; e < endp; e += 256) {
        int2 p = pay[e];
        int s = p.x & 0x00FFFFFF;
        float coef = ns[s] * __int_as_float(p.y);
        int pos = atomicAdd(&cur[(p.x >> 24) & 255], 1);
        es[pos] = make_int2(s, __float_as_int(coef));
    }
}

// ================= dense compute =================

__global__ void x2f8_kernel(const float* __restrict__ x, unsigned char* __restrict__ o8,
                            long long total4) {
    long long i = (long long)blockIdx.x * blockDim.x + threadIdx.x;
    if (i < total4) {
        float4 v = *reinterpret_cast<const float4*>(&x[i * 4]);
        unsigned int q = __builtin_amdgcn_cvt_pk_fp8_f32(v.x, v.y, 0u, false);
        q = __builtin_amdgcn_cvt_pk_fp8_f32(v.z, v.w, q, true);
        *reinterpret_cast<unsigned int*>(&o8[i * 4]) = q;
    }
}

__global__ void packW_kernel(const float* __restrict__ W, unsigned short* __restrict__ Wp,
                             int FI, int FO) {
    int KB = (FI + 31) / 32;
    int NB = FO / 16;
    int gid = blockIdx.x * blockDim.x + threadIdx.x;
    if (gid >= KB * NB * 64) return;
    int l = gid & 63;
    int tile = gid >> 6;
    int kb = tile % KB;
    int nb = tile / KB;
    int n = nb * 16 + (l & 15);
    int k0 = kb * 32 + (l >> 4) * 8;
    unsigned short tmp[8];
    #pragma unroll
    for (int j = 0; j < 8; ++j) {
        int k = k0 + j;
        tmp[j] = (k < FI) ? f2bf(W[(size_t)k * FO + n]) : (unsigned short)0;
    }
    *reinterpret_cast<uint4*>(&Wp[(size_t)gid * 8]) = *reinterpret_cast<uint4*>(tmp);
}

// ---------------- fp8 gather accumulate: 16 features/lane ----------------
#define F8ACC16(v, cc) { \
    auto q0 = __builtin_amdgcn_cvt_pk_f32_fp8((v).x, false); \
    auto q1 = __builtin_amdgcn_cvt_pk_f32_fp8((v).x, true);  \
    auto q2 = __builtin_amdgcn_cvt_pk_f32_fp8((v).y, false); \
    auto q3 = __builtin_amdgcn_cvt_pk_f32_fp8((v).y, true);  \
    auto q4 = __builtin_amdgcn_cvt_pk_f32_fp8((v).z, false); \
    auto q5 = __builtin_amdgcn_cvt_pk_f32_fp8((v).z, true);  \
    auto q6 = __builtin_amdgcn_cvt_pk_f32_fp8((v).w, false); \
    auto q7 = __builtin_amdgcn_cvt_pk_f32_fp8((v).w, true);  \
    a[0] = fmaf(q0[0], cc, a[0]);  a[1] = fmaf(q0[1], cc, a[1]); \
    a[2] = fmaf(q1[0], cc, a[2]);  a[3] = fmaf(q1[1], cc, a[3]); \
    a[4] = fmaf(q2[0], cc, a[4]);  a[5] = fmaf(q2[1], cc, a[5]); \
    a[6] = fmaf(q3[0], cc, a[6]);  a[7] = fmaf(q3[1], cc, a[7]); \
    a[8] = fmaf(q4[0], cc, a[8]);  a[9] = fmaf(q4[1], cc, a[9]); \
    a[10] = fmaf(q5[0], cc, a[10]); a[11] = fmaf(q5[1], cc, a[11]); \
    a[12] = fmaf(q6[0], cc, a[12]); a[13] = fmaf(q6[1], cc, a[13]); \
    a[14] = fmaf(q7[0], cc, a[14]); a[15] = fmaf(q7[1], cc, a[15]); }

// ---------------- CSR gather-sum aggregation (fp8 in) ----------------
// MODE 0: out16 = bf16(agg), no epilogue      (A-layer pre-mm)
// MODE 2: out8  = fp8(leaky(agg*nd+b)) only   (B-layer final; bf16 copy is dead)
template<int MODE>
__global__ void agg_kernel(const unsigned char* __restrict__ h8,
                           const int* __restrict__ rowptr, const int2* __restrict__ es,
                           const float* __restrict__ nd, const float* __restrict__ bias,
                           unsigned short* __restrict__ out16, unsigned char* __restrict__ out8,
                           int n, int jt, int ng) {
    int g = threadIdx.x / jt;
    if (g >= ng) return;
    int i = blockIdx.x * ng + g;
    if (i >= n) return;
    int c = (threadIdx.x - g * jt) << 4;   // feature offset (16 per lane)
    int F = jt << 4;
    int beg = rowptr[i], end = rowptr[i + 1];
    float a[16] = {};
    int e = beg;
    for (; e + 4 <= end; e += 4) {
        int2 e0 = es[e + 0], e1 = es[e + 1], e2 = es[e + 2], e3 = es[e + 3];
        uint4 v0 = *reinterpret_cast<const uint4*>(&h8[(size_t)e0.x * F + c]);
        uint4 v1 = *reinterpret_cast<const uint4*>(&h8[(size_t)e1.x * F + c]);
        uint4 v2 = *reinterpret_cast<const uint4*>(&h8[(size_t)e2.x * F + c]);
        uint4 v3 = *reinterpret_cast<const uint4*>(&h8[(size_t)e3.x * F + c]);
        float c0 = __int_as_float(e0.y), c1 = __int_as_float(e1.y);
        float c2 = __int_as_float(e2.y), c3 = __int_as_float(e3.y);
        F8ACC16(v0, c0)
        F8ACC16(v1, c1)
        F8ACC16(v2, c2)
        F8ACC16(v3, c3)
    }
    for (; e < end; ++e) {
        int2 e0 = es[e];
        uint4 v0 = *reinterpret_cast<const uint4*>(&h8[(size_t)e0.x * F + c]);
        float c0 = __int_as_float(e0.y);
        F8ACC16(v0, c0)
    }
    if constexpr (MODE == 2) {
        float s = nd[i];
        #pragma unroll
        for (int j = 0; j < 16; ++j) {
            float v = a[j] * s + bias[c + j];
            a[j] = LEAKY(v);
        }
        uint4 q;
        q.x = __builtin_amdgcn_cvt_pk_fp8_f32(a[0], a[1], 0u, false);
        q.x = __builtin_amdgcn_cvt_pk_fp8_f32(a[2], a[3], q.x, true);
        q.y = __builtin_amdgcn_cvt_pk_fp8_f32(a[4], a[5], 0u, false);
        q.y = __builtin_amdgcn_cvt_pk_fp8_f32(a[6], a[7], q.y, true);
        q.z = __builtin_amdgcn_cvt_pk_fp8_f32(a[8], a[9], 0u, false);
        q.z = __builtin_amdgcn_cvt_pk_fp8_f32(a[10], a[11], q.z, true);
        q.w = __builtin_amdgcn_cvt_pk_fp8_f32(a[12], a[13], 0u, false);
        q.w = __builtin_amdgcn_cvt_pk_fp8_f32(a[14], a[15], q.w, true);
        *reinterpret_cast<uint4*>(&out8[(size_t)i * F + c]) = q;
    } else {
        uint4 p0, p1;
        p0.x = pack2bf(a[0], a[1]);   p0.y = pack2bf(a[2], a[3]);
        p0.z = pack2bf(a[4], a[5]);   p0.w = pack2bf(a[6], a[7]);
        p1.x = pack2bf(a[8], a[9]);   p1.y = pack2bf(a[10], a[11]);
        p1.z = pack2bf(a[12], a[13]); p1.w = pack2bf(a[14], a[15]);
        *reinterpret_cast<uint4*>(&out16[(size_t)i * F + c]) = p0;
        *reinterpret_cast<uint4*>(&out16[(size_t)i * F + c + 8]) = p1;
    }
}

// ---------------- MFMA matmul: out[n x FO] = A[n x FI] @ W ----------------
// MODE 0: raw fp8 out                    (B-layer pre-agg)
// MODE 2: epilogue, bf16 out only        (A-layer, next consumer reads bf16)
// MODE 3: epilogue, fp8 out only         (A-layer, bf16 copy is dead)
template<int FI, int FO, int MODE>
__global__ __launch_bounds__(256) void mm_mfma_kernel(
    const unsigned short* __restrict__ Ab, const float* __restrict__ nd,
    const unsigned short* __restrict__ Wp, const float* __restrict__ bias,
    unsigned short* __restrict__ out16, unsigned char* __restrict__ out8, int n)
{
    constexpr int FIP = (FI + 31) / 32 * 32;
    constexpr int KB = FIP / 32;
    constexpr int NB = FO / 16;
    constexpr int LDA = FIP + 8;
    constexpr int RW = FIP / 8;
    __shared__ unsigned short As[64 * LDA];

    const int t = threadIdx.x;
    const int row0 = blockIdx.x * 64;

    for (int idx = t; idx < 64 * RW; idx += 256) {
        int r = idx / RW;
        int c8 = (idx - r * RW) * 8;
        int grow = row0 + r;
        uint4 v = make_uint4(0u, 0u, 0u, 0u);
        if (grow < n && c8 < FI)
            v = *reinterpret_cast<const uint4*>(&Ab[(size_t)grow * FI + c8]);
        *reinterpret_cast<uint4*>(&As[r * LDA + c8]) = v;
    }
    __syncthreads();

    const int w = t >> 6;
    const int l = t & 63;
    const int arow = (w << 4) + (l & 15);
    const int koff = (l >> 4) << 3;

    bf16x8 a[KB];
    #pragma unroll
    for (int kb = 0; kb < KB; ++kb)
        a[kb] = *reinterpret_cast<const bf16x8*>(&As[arow * LDA + kb * 32 + koff]);

    f32x4 acc[NB] = {};
    #pragma unroll
    for (int nb = 0; nb < NB; ++nb) {
        #pragma unroll
        for (int kb = 0; kb < KB; ++kb) {
            bf16x8 b = *reinterpret_cast<const bf16x8*>(&Wp[(size_t)((nb * KB + kb) * 64 + l) * 8]);
            acc[nb] = __builtin_amdgcn_mfma_f32_16x16x32_bf16(a[kb], b, acc[nb], 0, 0, 0);
        }
    }

    const int col = l & 15;
    const int rb = (l >> 4) << 2;
    #pragma unroll
    for (int r = 0; r < 4; ++r) {
        int grow = row0 + (w << 4) + rb + r;
        if (grow < n) {
            float s = (MODE != 0) ? nd[grow] : 1.0f;
            #pragma unroll
            for (int nb = 0; nb < NB; ++nb) {
                float v = acc[nb][r];
                if (MODE == 0) {
                    out8[(size_t)grow * FO + nb * 16 + col] = f2f8(v);
                } else {
                    v = v * s + bias[nb * 16 + col];
                    v = LEAKY(v);
                    if (MODE == 2)
                        out16[(size_t)grow * FO + nb * 16 + col] = f2bf(v);
                    else
                        out8[(size_t)grow * FO + nb * 16 + col] = f2f8(v);
                }
            }
        }
    }
}

// ---------------- mean over nodes (bf16 in, F=160) ----------------
__global__ __launch_bounds__(320) void mean_kernel(const unsigned short* __restrict__ h,
                                                   float* __restrict__ acc, int n) {
    __shared__ float lacc[160];
    int t = threadIdx.x;
    for (int j = t; j < 160; j += 320) lacc[j] = 0.0f;
    __syncthreads();
    int lane = t % 20;
    int rg = t / 20;
    float a0 = 0, a1 = 0, a2 = 0, a3 = 0, a4 = 0, a5 = 0, a6 = 0, a7 = 0;
    for (int i = blockIdx.x * 16 + rg; i < n; i += gridDim.x * 16) {
        uint4 v = *reinterpret_cast<const uint4*>(&h[(size_t)i * 160 + lane * 8]);
        a0 += bflo(v.x); a1 += bfhi(v.x);
        a2 += bflo(v.y); a3 += bfhi(v.y);
        a4 += bflo(v.z); a5 += bfhi(v.z);
        a6 += bflo(v.w); a7 += bfhi(v.w);
    }
    int c = lane * 8;
    atomicAdd(&lacc[c + 0], a0); atomicAdd(&lacc[c + 1], a1);
    atomicAdd(&lacc[c + 2], a2); atomicAdd(&lacc[c + 3], a3);
    atomicAdd(&lacc[c + 4], a4); atomicAdd(&lacc[c + 5], a5);
    atomicAdd(&lacc[c + 6], a6); atomicAdd(&lacc[c + 7], a7);
    __syncthreads();
    for (int j = t; j < 160; j += 320) atomicAdd(&acc[j], lacc[j]);
}

// ---------------- head ----------------
__global__ void head_kernel(const float* __restrict__ acc, const float* __restrict__ Wd1,
                            const float* __restrict__ bd1, const float* __restrict__ Wd2,
                            const float* __restrict__ bd2, float* __restrict__ out, int n) {
    __shared__ float gm[160];
    __shared__ float h1[140];
    int tid = threadIdx.x;
    if (tid < 160) {
        float v = acc[tid] / (float)n;
        gm[tid] = LEAKY(v);
    }
    __syncthreads();
    if (tid < 140) {
        float s = bd1[tid];
        for (int k = 0; k < 160; ++k) s += gm[k] * Wd1[k * 140 + tid];
        h1[tid] = LEAKY(s);
    }
    __syncthreads();
    if (tid < 2) {
        float s = bd2[tid];
        for (int k = 0; k < 140; ++k) s += h1[k] * Wd2[k * 2 + tid];
        out[tid] = 1.0f / (1.0f + expf(-s));
    }
}

extern "C" void kernel_launch(void* const* d_in, const int* in_sizes, int n_in,
                              void* d_out, int out_size, void* d_ws, size_t ws_size,
                              hipStream_t stream) {
    static const int dims[12] = {64, 80, 160, 112, 160, 176, 96, 144, 96, 128, 96, 160};

    const float* x     = (const float*)d_in[0];
    const int*   src   = (const int*)d_in[1];
    const int*   dst   = (const int*)d_in[2];
    const float* edata = (const float*)d_in[3];
    const float* W[11];
    const float* B[11];
    for (int i = 0; i < 11; ++i) {
        W[i] = (const float*)d_in[4 + 2 * i];
        B[i] = (const float*)d_in[5 + 2 * i];
    }
    const float* Wd1   = (const float*)d_in[26];
    const float* bd1   = (const float*)d_in[27];
    const float* Wd2   = (const float*)d_in[28];
    const float* bd2   = (const float*)d_in[29];
    const float* mu    = (const float*)d_in[30];
    const float* sigma = (const float*)d_in[31];
    float* out = (float*)d_out;

    const int N = in_sizes[0] / 64;
    const int E = in_sizes[1];
    const int FMAX = 176;

    const int NBK  = (N + BKN - 1) / BKN;
    const int NBLK = (E + EPB - 1) / EPB;
    const int LEN  = NBK * NBLK;

    size_t woff[11];
    size_t wtot = 0;
    for (int l = 0; l < 11; ++l) {
        woff[l] = wtot;
        int fip = (dims[l] + 31) / 32 * 32;
        wtot += (size_t)fip * dims[l + 1];
    }

    char* wsb = (char*)d_ws;
    size_t o = 0;
    auto alloc = [&](size_t bytes) { void* p = wsb + o; o += (bytes + 255) & ~(size_t)255; return p; };
    unsigned short* hb_main = (unsigned short*)alloc((size_t)N * FMAX * 2);
    unsigned short* hb_t    = (unsigned short*)alloc((size_t)N * FMAX * 2);
    unsigned char*  h8_main = (unsigned char*) alloc((size_t)N * FMAX);
    unsigned char*  h8_t    = (unsigned char*) alloc((size_t)N * FMAX);
    unsigned short* Wp  = (unsigned short*)alloc(wtot * 2);
    int2*  es      = (int2*) alloc((size_t)E * sizeof(int2));
    int2*  pay     = (int2*) alloc((size_t)E * sizeof(int2));
    unsigned char* srcb8 = (unsigned char*)alloc((size_t)E);
    int*   bh      = (int*)  alloc((size_t)(2 * LEN) * sizeof(int));
    int*   bhs     = (int*)  alloc((size_t)(2 * LEN + 1) * sizeof(int));
    int*   rowptr  = (int*)  alloc((size_t)(N + 1) * sizeof(int));
    float* ns      = (float*)alloc((size_t)N * sizeof(float));
    float* nd      = (float*)alloc((size_t)N * sizeof(float));
    int*   bsums   = (int*)  alloc(2048 * sizeof(int));
    float* acc     = (float*)alloc(160 * sizeof(float));

    // ---- bucket-sort CSR pipeline ----
    histo_kernel<<<NBLK, 512, 2 * NBK * sizeof(int), stream>>>(src, dst, bh, E, NBK, NBLK, LEN);
    int snb = (2 * LEN + SCAN_BLK - 1) / SCAN_BLK;
    scan1_kernel<<<snb, SCAN_BLK, 0, stream>>>(bh, bhs, bsums, 2 * LEN);
    scan2_kernel<<<1, SCAN_BLK, 0, stream>>>(bsums, snb);
    scan3_kernel<<<snb, SCAN_BLK, 0, stream>>>(bhs, bsums, 2 * LEN);
    scat_kernel<<<NBLK, 512, 2 * NBK * sizeof(int), stream>>>(src, dst, edata, mu, sigma,
                                                              bhs, srcb8, pay, E, NBK, NBLK, LEN);
    ns_kernel<<<NBK, 256, 0, stream>>>(srcb8, bhs, ns, N, NBLK);
    csr_kernel<<<NBK, 256, 0, stream>>>(pay, ns, bhs, rowptr, nd, es, N, E, NBK, NBLK, LEN);

    // ---- x -> fp8 ; W -> packed bf16 fragments ----
    long long x4 = (long long)N * 64 / 4;
    x2f8_kernel<<<(int)((x4 + 255) / 256), 256, 0, stream>>>(x, h8_main, x4);
    for (int l = 0; l < 11; ++l) {
        int fip = (dims[l] + 31) / 32 * 32;
        int threads = (fip / 32) * (dims[l + 1] / 16) * 64;
        packW_kernel<<<(threads + 255) / 256, 256, 0, stream>>>(W[l], Wp + woff[l],
                                                                dims[l], dims[l + 1]);
    }

    // ---- 11 GCN layers ----
    const int mmgrid = (N + 63) / 64;

    // order A (FO >= FI): agg (bf16, no epi) -> hb_t; mm epi -> bf16 (MM=2) or fp8 (MM=3)
    #define DO_A(FI, FO, l, MM) { \
        constexpr int jt = FI / 16; constexpr int ng = 256 / jt; \
        agg_kernel<0><<<(N + ng - 1) / ng, 256, 0, stream>>>( \
            h8_main, rowptr, es, nd, B[l], hb_t, nullptr, N, jt, ng); \
        mm_mfma_kernel<FI, FO, MM><<<mmgrid, 256, 0, stream>>>( \
            hb_t, nd, Wp + woff[l], B[l], hb_main, h8_main, N); }

    // order B (FO < FI): mm raw -> h8_t (fp8); agg epi -> h8_main (fp8 only)
    #define DO_B(FI, FO, l) { \
        mm_mfma_kernel<FI, FO, 0><<<mmgrid, 256, 0, stream>>>( \
            hb_main, nd, Wp + woff[l], B[l], nullptr, h8_t, N); \
        constexpr int jt = FO / 16; constexpr int ng = 256 / jt; \
        agg_kernel<2><<<(N + ng - 1) / ng, 256, 0, stream>>>( \
            h8_t, rowptr, es, nd, B[l], nullptr, h8_main, N, jt, ng); }

    DO_A(64, 80, 0, 3)      // next L1 is A: fp8 only (bf16 dead)
    DO_A(80, 160, 1, 2)     // next L2 is B: bf16 only
    DO_B(160, 112, 2)
    DO_A(112, 160, 3, 3)    // next L4 is A: fp8 only
    DO_A(160, 176, 4, 2)    // next L5 is B
    DO_B(176, 96, 5)
    DO_A(96, 144, 6, 2)     // next L7 is B
    DO_B(144, 96, 7)
    DO_A(96, 128, 8, 2)     // next L9 is B
    DO_B(128, 96, 9)
    DO_A(96, 160, 10, 2)    // next is mean: bf16 only

    #undef DO_A
    #undef DO_B

    // ---- mean over nodes -> head ----
    hipMemsetAsync(acc, 0, 160 * sizeof(float), stream);
    mean_kernel<<<256, 320, 0, stream>>>(hb_main, acc, N);
    head_kernel<<<1, 256, 0, stream>>>(acc, Wd1, bd1, Wd2, bd2, out, N);
}

// Round 14
// 1261.416 us; speedup vs baseline: 1.0493x; 1.0125x over previous
//
#include <hip/hip_runtime.h>

#define LEAKY(v) ((v) > 0.0f ? (v) : 0.01f * (v))
#define SCAN_BLK 1024
#define EPB 8192          // edges per block in bucket pipeline
#define BKN 512           // nodes per bucket (9-bit local id)
#define SRCM 0x1FFFF      // 17-bit src mask (N = 100K < 2^17)

typedef __bf16 bf16x8 __attribute__((ext_vector_type(8)));
typedef float f32x4 __attribute__((ext_vector_type(4)));

// ---------------- bf16 helpers (RNE) ----------------
__device__ inline float bflo(unsigned int u) { return __uint_as_float(u << 16); }
__device__ inline float bfhi(unsigned int u) { return __uint_as_float(u & 0xFFFF0000u); }
__device__ inline unsigned int pack2bf(float lo, float hi) {
    unsigned int a = __float_as_uint(lo);
    unsigned int b = __float_as_uint(hi);
    a = (a + 0x7FFFu + ((a >> 16) & 1u)) >> 16;
    b = (b + 0x7FFFu + ((b >> 16) & 1u)) & 0xFFFF0000u;
    return a | b;
}
__device__ inline unsigned short f2bf(float f) {
    unsigned int u = __float_as_uint(f);
    return (unsigned short)((u + 0x7FFFu + ((u >> 16) & 1u)) >> 16);
}

// ---------------- fp8 e4m3 helpers (HW cvt, OCP on gfx950) ----------------
__device__ inline unsigned char f2f8(float v) {
    return (unsigned char)(__builtin_amdgcn_cvt_pk_fp8_f32(v, 0.0f, 0u, false) & 0xFFu);
}

// ================= bucket-sort CSR pipeline (no global atomics) =================

__global__ void histo_kernel(const int* __restrict__ src, const int* __restrict__ dst,
                             int* __restrict__ bh, int E, int NBK, int NBLK, int LEN) {
    extern __shared__ int lds[];           // 2*NBK ints
    int* hs = lds;
    int* hd = lds + NBK;
    for (int j = threadIdx.x; j < 2 * NBK; j += 512) lds[j] = 0;
    __syncthreads();
    int b = blockIdx.x;
    int e0 = b * EPB, e1 = min(e0 + EPB, E);
    for (int e = e0 + threadIdx.x; e < e1; e += 512) {
        atomicAdd(&hs[src[e] >> 9], 1);
        atomicAdd(&hd[dst[e] >> 9], 1);
    }
    __syncthreads();
    for (int j = threadIdx.x; j < NBK; j += 512) {
        bh[j * NBLK + b] = hs[j];
        bh[LEN + j * NBLK + b] = hd[j];
    }
}

__global__ void scan1_kernel(const int* __restrict__ deg, int* __restrict__ out,
                             int* __restrict__ bsums, int n) {
    __shared__ int sh[SCAN_BLK];
    int gid = blockIdx.x * SCAN_BLK + threadIdx.x;
    int v = (gid < n) ? deg[gid] : 0;
    sh[threadIdx.x] = v;
    __syncthreads();
    for (int off = 1; off < SCAN_BLK; off <<= 1) {
        int t = (threadIdx.x >= off) ? sh[threadIdx.x - off] : 0;
        __syncthreads();
        sh[threadIdx.x] += t;
        __syncthreads();
    }
    if (gid < n) out[gid + 1] = sh[threadIdx.x];
    if (threadIdx.x == SCAN_BLK - 1) bsums[blockIdx.x] = sh[threadIdx.x];
    if (gid == 0) out[0] = 0;
}

__global__ void scan2_kernel(int* __restrict__ bsums, int nb) {
    __shared__ int sh[SCAN_BLK];
    int v = (threadIdx.x < nb) ? bsums[threadIdx.x] : 0;
    sh[threadIdx.x] = v;
    __syncthreads();
    for (int off = 1; off < SCAN_BLK; off <<= 1) {
        int t = (threadIdx.x >= off) ? sh[threadIdx.x - off] : 0;
        __syncthreads();
        sh[threadIdx.x] += t;
        __syncthreads();
    }
    if (threadIdx.x < nb) bsums[threadIdx.x] = sh[threadIdx.x] - v;
}

__global__ void scan3_kernel(int* __restrict__ out, const int* __restrict__ bsums, int n) {
    int gid = blockIdx.x * SCAN_BLK + threadIdx.x;
    if (gid < n) out[gid + 1] += bsums[blockIdx.x];
}

// merged scatter: src local-ids (2B) into src buckets; (s | local_d<<17, w) into dst buckets
__global__ void scat_kernel(const int* __restrict__ src, const int* __restrict__ dst,
                            const float* __restrict__ edata,
                            const float* __restrict__ mu, const float* __restrict__ sigma,
                            const int* __restrict__ bhs, unsigned short* __restrict__ srcb,
                            int2* __restrict__ pay, int E, int NBK, int NBLK, int LEN) {
    extern __shared__ int cur[];           // 2*NBK ints
    int* cs = cur;
    int* cd = cur + NBK;
    int b = blockIdx.x;
    for (int j = threadIdx.x; j < NBK; j += 512) {
        cs[j] = bhs[j * NBLK + b];
        cd[j] = bhs[LEN + j * NBLK + b] - E;
    }
    __syncthreads();
    int e0 = b * EPB, e1 = min(e0 + EPB, E);
    for (int e = e0 + threadIdx.x; e < e1; e += 512) {
        int s = src[e];
        int d = dst[e];
        float ed = edata[e];
        float dd = ed - mu[0];
        float w = (ed == 1.0f) ? ed : expf(-(dd * dd) / sigma[0]);
        int ps = atomicAdd(&cs[s >> 9], 1);
        srcb[ps] = (unsigned short)(s & (BKN - 1));
        int pd = atomicAdd(&cd[d >> 9], 1);
        pay[pd] = make_int2(s | ((d & (BKN - 1)) << 17), __float_as_int(w));
    }
}

__global__ void ns_kernel(const unsigned short* __restrict__ srcb, const int* __restrict__ bhs,
                          float* __restrict__ ns, int n, int NBLK) {
    __shared__ int cnt[BKN];
    int b = blockIdx.x;
    int j = threadIdx.x;
    cnt[j] = 0;
    __syncthreads();
    int base = bhs[b * NBLK];
    int endp = bhs[(b + 1) * NBLK];
    for (int e = base + j; e < endp; e += BKN)
        atomicAdd(&cnt[srcb[e]], 1);
    __syncthreads();
    int node = b * BKN + j;
    if (node < n) {
        int c = cnt[j];
        ns[node] = (c > 0) ? rsqrtf((float)c) : 0.0f;
    }
}

__global__ void csr_kernel(const int2* __restrict__ pay, const float* __restrict__ ns,
                           const int* __restrict__ bhs, int* __restrict__ rowptr,
                           float* __restrict__ nd, int2* __restrict__ es,
                           int n, int E, int NBK, int NBLK, int LEN) {
    __shared__ int cnt[BKN];
    __shared__ int cur[BKN];
    int b = blockIdx.x;
    int j = threadIdx.x;
    cnt[j] = 0;
    __syncthreads();
    int base = bhs[LEN + b * NBLK] - E;
    int endp = bhs[LEN + (b + 1) * NBLK] - E;
    for (int e = base + j; e < endp; e += BKN)
        atomicAdd(&cnt[(pay[e].x >> 17) & (BKN - 1)], 1);
    __syncthreads();
    int c0 = cnt[j];
    for (int off = 1; off < BKN; off <<= 1) {
        int t = (j >= off) ? cnt[j - off] : 0;
        __syncthreads();
        cnt[j] += t;
        __syncthreads();
    }
    int excl = cnt[j] - c0;
    cur[j] = base + excl;
    int node = b * BKN + j;
    if (node < n) {
        rowptr[node] = base + excl;
        nd[node] = (c0 > 0) ? rsqrtf((float)c0) : 0.0f;
    }
    if (b == NBK - 1 && j == 0) rowptr[n] = E;
    __syncthreads();
    for (int e = base + j; e < endp; e += BKN) {
        int2 p = pay[e];
        int s = p.x & SRCM;
        float coef = ns[s] * __int_as_float(p.y);
        int pos = atomicAdd(&cur[(p.x >> 17) & (BKN - 1)], 1);
        es[pos] = make_int2(s, __float_as_int(coef));
    }
}

// ================= dense compute =================

__global__ void x2f8_kernel(const float* __restrict__ x, unsigned char* __restrict__ o8,
                            long long total4) {
    long long i = (long long)blockIdx.x * blockDim.x + threadIdx.x;
    if (i < total4) {
        float4 v = *reinterpret_cast<const float4*>(&x[i * 4]);
        unsigned int q = __builtin_amdgcn_cvt_pk_fp8_f32(v.x, v.y, 0u, false);
        q = __builtin_amdgcn_cvt_pk_fp8_f32(v.z, v.w, q, true);
        *reinterpret_cast<unsigned int*>(&o8[i * 4]) = q;
    }
}

__global__ void packW_kernel(const float* __restrict__ W, unsigned short* __restrict__ Wp,
                             int FI, int FO) {
    int KB = (FI + 31) / 32;
    int NB = FO / 16;
    int gid = blockIdx.x * blockDim.x + threadIdx.x;
    if (gid >= KB * NB * 64) return;
    int l = gid & 63;
    int tile = gid >> 6;
    int kb = tile % KB;
    int nb = tile / KB;
    int n = nb * 16 + (l & 15);
    int k0 = kb * 32 + (l >> 4) * 8;
    unsigned short tmp[8];
    #pragma unroll
    for (int j = 0; j < 8; ++j) {
        int k = k0 + j;
        tmp[j] = (k < FI) ? f2bf(W[(size_t)k * FO + n]) : (unsigned short)0;
    }
    *reinterpret_cast<uint4*>(&Wp[(size_t)gid * 8]) = *reinterpret_cast<uint4*>(tmp);
}

// ---------------- fp8 gather accumulate: 16 features/lane ----------------
#define F8ACC16(v, cc) { \
    auto q0 = __builtin_amdgcn_cvt_pk_f32_fp8((v).x, false); \
    auto q1 = __builtin_amdgcn_cvt_pk_f32_fp8((v).x, true);  \
    auto q2 = __builtin_amdgcn_cvt_pk_f32_fp8((v).y, false); \
    auto q3 = __builtin_amdgcn_cvt_pk_f32_fp8((v).y, true);  \
    auto q4 = __builtin_amdgcn_cvt_pk_f32_fp8((v).z, false); \
    auto q5 = __builtin_amdgcn_cvt_pk_f32_fp8((v).z, true);  \
    auto q6 = __builtin_amdgcn_cvt_pk_f32_fp8((v).w, false); \
    auto q7 = __builtin_amdgcn_cvt_pk_f32_fp8((v).w, true);  \
    a[0] = fmaf(q0[0], cc, a[0]);  a[1] = fmaf(q0[1], cc, a[1]); \
    a[2] = fmaf(q1[0], cc, a[2]);  a[3] = fmaf(q1[1], cc, a[3]); \
    a[4] = fmaf(q2[0], cc, a[4]);  a[5] = fmaf(q2[1], cc, a[5]); \
    a[6] = fmaf(q3[0], cc, a[6]);  a[7] = fmaf(q3[1], cc, a[7]); \
    a[8] = fmaf(q4[0], cc, a[8]);  a[9] = fmaf(q4[1], cc, a[9]); \
    a[10] = fmaf(q5[0], cc, a[10]); a[11] = fmaf(q5[1], cc, a[11]); \
    a[12] = fmaf(q6[0], cc, a[12]); a[13] = fmaf(q6[1], cc, a[13]); \
    a[14] = fmaf(q7[0], cc, a[14]); a[15] = fmaf(q7[1], cc, a[15]); }

// ---------------- CSR gather-sum aggregation (fp8 in) ----------------
// MODE 0: out16 = bf16(agg), no epilogue      (A-layer pre-mm)
// MODE 2: out8  = fp8(leaky(agg*nd+b)) only   (B-layer final; bf16 copy is dead)
template<int MODE>
__global__ void agg_kernel(const unsigned char* __restrict__ h8,
                           const int* __restrict__ rowptr, const int2* __restrict__ es,
                           const float* __restrict__ nd, const float* __restrict__ bias,
                           unsigned short* __restrict__ out16, unsigned char* __restrict__ out8,
                           int n, int jt, int ng) {
    int g = threadIdx.x / jt;
    if (g >= ng) return;
    int i = blockIdx.x * ng + g;
    if (i >= n) return;
    int c = (threadIdx.x - g * jt) << 4;   // feature offset (16 per lane)
    int F = jt << 4;
    int beg = rowptr[i], end = rowptr[i + 1];
    float a[16] = {};
    int e = beg;
    for (; e + 4 <= end; e += 4) {
        int2 e0 = es[e + 0], e1 = es[e + 1], e2 = es[e + 2], e3 = es[e + 3];
        uint4 v0 = *reinterpret_cast<const uint4*>(&h8[(size_t)e0.x * F + c]);
        uint4 v1 = *reinterpret_cast<const uint4*>(&h8[(size_t)e1.x * F + c]);
        uint4 v2 = *reinterpret_cast<const uint4*>(&h8[(size_t)e2.x * F + c]);
        uint4 v3 = *reinterpret_cast<const uint4*>(&h8[(size_t)e3.x * F + c]);
        float c0 = __int_as_float(e0.y), c1 = __int_as_float(e1.y);
        float c2 = __int_as_float(e2.y), c3 = __int_as_float(e3.y);
        F8ACC16(v0, c0)
        F8ACC16(v1, c1)
        F8ACC16(v2, c2)
        F8ACC16(v3, c3)
    }
    for (; e < end; ++e) {
        int2 e0 = es[e];
        uint4 v0 = *reinterpret_cast<const uint4*>(&h8[(size_t)e0.x * F + c]);
        float c0 = __int_as_float(e0.y);
        F8ACC16(v0, c0)
    }
    if constexpr (MODE == 2) {
        float s = nd[i];
        #pragma unroll
        for (int j = 0; j < 16; ++j) {
            float v = a[j] * s + bias[c + j];
            a[j] = LEAKY(v);
        }
        uint4 q;
        q.x = __builtin_amdgcn_cvt_pk_fp8_f32(a[0], a[1], 0u, false);
        q.x = __builtin_amdgcn_cvt_pk_fp8_f32(a[2], a[3], q.x, true);
        q.y = __builtin_amdgcn_cvt_pk_fp8_f32(a[4], a[5], 0u, false);
        q.y = __builtin_amdgcn_cvt_pk_fp8_f32(a[6], a[7], q.y, true);
        q.z = __builtin_amdgcn_cvt_pk_fp8_f32(a[8], a[9], 0u, false);
        q.z = __builtin_amdgcn_cvt_pk_fp8_f32(a[10], a[11], q.z, true);
        q.w = __builtin_amdgcn_cvt_pk_fp8_f32(a[12], a[13], 0u, false);
        q.w = __builtin_amdgcn_cvt_pk_fp8_f32(a[14], a[15], q.w, true);
        *reinterpret_cast<uint4*>(&out8[(size_t)i * F + c]) = q;
    } else {
        uint4 p0, p1;
        p0.x = pack2bf(a[0], a[1]);   p0.y = pack2bf(a[2], a[3]);
        p0.z = pack2bf(a[4], a[5]);   p0.w = pack2bf(a[6], a[7]);
        p1.x = pack2bf(a[8], a[9]);   p1.y = pack2bf(a[10], a[11]);
        p1.z = pack2bf(a[12], a[13]); p1.w = pack2bf(a[14], a[15]);
        *reinterpret_cast<uint4*>(&out16[(size_t)i * F + c]) = p0;
        *reinterpret_cast<uint4*>(&out16[(size_t)i * F + c + 8]) = p1;
    }
}

// ---------------- MFMA matmul: out[n x FO] = A[n x FI] @ W ----------------
// MODE 0: raw fp8 out                    (B-layer pre-agg)
// MODE 2: epilogue, bf16 out only        (A-layer, next consumer reads bf16)
// MODE 3: epilogue, fp8 out only         (A-layer, bf16 copy is dead)
template<int FI, int FO, int MODE>
__global__ __launch_bounds__(256) void mm_mfma_kernel(
    const unsigned short* __restrict__ Ab, const float* __restrict__ nd,
    const unsigned short* __restrict__ Wp, const float* __restrict__ bias,
    unsigned short* __restrict__ out16, unsigned char* __restrict__ out8, int n)
{
    constexpr int FIP = (FI + 31) / 32 * 32;
    constexpr int KB = FIP / 32;
    constexpr int NB = FO / 16;
    constexpr int LDA = FIP + 8;
    constexpr int RW = FIP / 8;
    __shared__ unsigned short As[64 * LDA];

    const int t = threadIdx.x;
    const int row0 = blockIdx.x * 64;

    for (int idx = t; idx < 64 * RW; idx += 256) {
        int r = idx / RW;
        int c8 = (idx - r * RW) * 8;
        int grow = row0 + r;
        uint4 v = make_uint4(0u, 0u, 0u, 0u);
        if (grow < n && c8 < FI)
            v = *reinterpret_cast<const uint4*>(&Ab[(size_t)grow * FI + c8]);
        *reinterpret_cast<uint4*>(&As[r * LDA + c8]) = v;
    }
    __syncthreads();

    const int w = t >> 6;
    const int l = t & 63;
    const int arow = (w << 4) + (l & 15);
    const int koff = (l >> 4) << 3;

    bf16x8 a[KB];
    #pragma unroll
    for (int kb = 0; kb < KB; ++kb)
        a[kb] = *reinterpret_cast<const bf16x8*>(&As[arow * LDA + kb * 32 + koff]);

    f32x4 acc[NB] = {};
    #pragma unroll
    for (int nb = 0; nb < NB; ++nb) {
        #pragma unroll
        for (int kb = 0; kb < KB; ++kb) {
            bf16x8 b = *reinterpret_cast<const bf16x8*>(&Wp[(size_t)((nb * KB + kb) * 64 + l) * 8]);
            acc[nb] = __builtin_amdgcn_mfma_f32_16x16x32_bf16(a[kb], b, acc[nb], 0, 0, 0);
        }
    }

    const int col = l & 15;
    const int rb = (l >> 4) << 2;
    #pragma unroll
    for (int r = 0; r < 4; ++r) {
        int grow = row0 + (w << 4) + rb + r;
        if (grow < n) {
            float s = (MODE != 0) ? nd[grow] : 1.0f;
            #pragma unroll
            for (int nb = 0; nb < NB; ++nb) {
                float v = acc[nb][r];
                if (MODE == 0) {
                    out8[(size_t)grow * FO + nb * 16 + col] = f2f8(v);
                } else {
                    v = v * s + bias[nb * 16 + col];
                    v = LEAKY(v);
                    if (MODE == 2)
                        out16[(size_t)grow * FO + nb * 16 + col] = f2bf(v);
                    else
                        out8[(size_t)grow * FO + nb * 16 + col] = f2f8(v);
                }
            }
        }
    }
}

// ---------------- mean over nodes (bf16 in, F=160) ----------------
__global__ __launch_bounds__(320) void mean_kernel(const unsigned short* __restrict__ h,
                                                   float* __restrict__ acc, int n) {
    __shared__ float lacc[160];
    int t = threadIdx.x;
    for (int j = t; j < 160; j += 320) lacc[j] = 0.0f;
    __syncthreads();
    int lane = t % 20;
    int rg = t / 20;
    float a0 = 0, a1 = 0, a2 = 0, a3 = 0, a4 = 0, a5 = 0, a6 = 0, a7 = 0;
    for (int i = blockIdx.x * 16 + rg; i < n; i += gridDim.x * 16) {
        uint4 v = *reinterpret_cast<const uint4*>(&h[(size_t)i * 160 + lane * 8]);
        a0 += bflo(v.x); a1 += bfhi(v.x);
        a2 += bflo(v.y); a3 += bfhi(v.y);
        a4 += bflo(v.z); a5 += bfhi(v.z);
        a6 += bflo(v.w); a7 += bfhi(v.w);
    }
    int c = lane * 8;
    atomicAdd(&lacc[c + 0], a0); atomicAdd(&lacc[c + 1], a1);
    atomicAdd(&lacc[c + 2], a2); atomicAdd(&lacc[c + 3], a3);
    atomicAdd(&lacc[c + 4], a4); atomicAdd(&lacc[c + 5], a5);
    atomicAdd(&lacc[c + 6], a6); atomicAdd(&lacc[c + 7], a7);
    __syncthreads();
    for (int j = t; j < 160; j += 320) atomicAdd(&acc[j], lacc[j]);
}

// ---------------- head ----------------
__global__ void head_kernel(const float* __restrict__ acc, const float* __restrict__ Wd1,
                            const float* __restrict__ bd1, const float* __restrict__ Wd2,
                            const float* __restrict__ bd2, float* __restrict__ out, int n) {
    __shared__ float gm[160];
    __shared__ float h1[140];
    int tid = threadIdx.x;
    if (tid < 160) {
        float v = acc[tid] / (float)n;
        gm[tid] = LEAKY(v);
    }
    __syncthreads();
    if (tid < 140) {
        float s = bd1[tid];
        for (int k = 0; k < 160; ++k) s += gm[k] * Wd1[k * 140 + tid];
        h1[tid] = LEAKY(s);
    }
    __syncthreads();
    if (tid < 2) {
        float s = bd2[tid];
        for (int k = 0; k < 140; ++k) s += h1[k] * Wd2[k * 2 + tid];
        out[tid] = 1.0f / (1.0f + expf(-s));
    }
}

extern "C" void kernel_launch(void* const* d_in, const int* in_sizes, int n_in,
                              void* d_out, int out_size, void* d_ws, size_t ws_size,
                              hipStream_t stream) {
    static const int dims[12] = {64, 80, 160, 112, 160, 176, 96, 144, 96, 128, 96, 160};

    const float* x     = (const float*)d_in[0];
    const int*   src   = (const int*)d_in[1];
    const int*   dst   = (const int*)d_in[2];
    const float* edata = (const float*)d_in[3];
    const float* W[11];
    const float* B[11];
    for (int i = 0; i < 11; ++i) {
        W[i] = (const float*)d_in[4 + 2 * i];
        B[i] = (const float*)d_in[5 + 2 * i];
    }
    const float* Wd1   = (const float*)d_in[26];
    const float* bd1   = (const float*)d_in[27];
    const float* Wd2   = (const float*)d_in[28];
    const float* bd2   = (const float*)d_in[29];
    const float* mu    = (const float*)d_in[30];
    const float* sigma = (const float*)d_in[31];
    float* out = (float*)d_out;

    const int N = in_sizes[0] / 64;
    const int E = in_sizes[1];
    const int FMAX = 176;

    const int NBK  = (N + BKN - 1) / BKN;
    const int NBLK = (E + EPB - 1) / EPB;
    const int LEN  = NBK * NBLK;

    size_t woff[11];
    size_t wtot = 0;
    for (int l = 0; l < 11; ++l) {
        woff[l] = wtot;
        int fip = (dims[l] + 31) / 32 * 32;
        wtot += (size_t)fip * dims[l + 1];
    }

    char* wsb = (char*)d_ws;
    size_t o = 0;
    auto alloc = [&](size_t bytes) { void* p = wsb + o; o += (bytes + 255) & ~(size_t)255; return p; };
    unsigned short* hb_main = (unsigned short*)alloc((size_t)N * FMAX * 2);
    unsigned short* hb_t    = (unsigned short*)alloc((size_t)N * FMAX * 2);
    unsigned char*  h8_main = (unsigned char*) alloc((size_t)N * FMAX);
    unsigned char*  h8_t    = (unsigned char*) alloc((size_t)N * FMAX);
    unsigned short* Wp  = (unsigned short*)alloc(wtot * 2);
    int2*  es      = (int2*) alloc((size_t)E * sizeof(int2));
    int2*  pay     = (int2*) alloc((size_t)E * sizeof(int2));
    unsigned short* srcb = (unsigned short*)alloc((size_t)E * 2);
    int*   bh      = (int*)  alloc((size_t)(2 * LEN) * sizeof(int));
    int*   bhs     = (int*)  alloc((size_t)(2 * LEN + 1) * sizeof(int));
    int*   rowptr  = (int*)  alloc((size_t)(N + 1) * sizeof(int));
    float* ns      = (float*)alloc((size_t)N * sizeof(float));
    float* nd      = (float*)alloc((size_t)N * sizeof(float));
    int*   bsums   = (int*)  alloc(2048 * sizeof(int));
    float* acc     = (float*)alloc(160 * sizeof(float));

    // ---- bucket-sort CSR pipeline ----
    histo_kernel<<<NBLK, 512, 2 * NBK * sizeof(int), stream>>>(src, dst, bh, E, NBK, NBLK, LEN);
    int snb = (2 * LEN + SCAN_BLK - 1) / SCAN_BLK;
    scan1_kernel<<<snb, SCAN_BLK, 0, stream>>>(bh, bhs, bsums, 2 * LEN);
    scan2_kernel<<<1, SCAN_BLK, 0, stream>>>(bsums, snb);
    scan3_kernel<<<snb, SCAN_BLK, 0, stream>>>(bhs, bsums, 2 * LEN);
    scat_kernel<<<NBLK, 512, 2 * NBK * sizeof(int), stream>>>(src, dst, edata, mu, sigma,
                                                              bhs, srcb, pay, E, NBK, NBLK, LEN);
    ns_kernel<<<NBK, BKN, 0, stream>>>(srcb, bhs, ns, N, NBLK);
    csr_kernel<<<NBK, BKN, 0, stream>>>(pay, ns, bhs, rowptr, nd, es, N, E, NBK, NBLK, LEN);

    // ---- x -> fp8 ; W -> packed bf16 fragments ----
    long long x4 = (long long)N * 64 / 4;
    x2f8_kernel<<<(int)((x4 + 255) / 256), 256, 0, stream>>>(x, h8_main, x4);
    for (int l = 0; l < 11; ++l) {
        int fip = (dims[l] + 31) / 32 * 32;
        int threads = (fip / 32) * (dims[l + 1] / 16) * 64;
        packW_kernel<<<(threads + 255) / 256, 256, 0, stream>>>(W[l], Wp + woff[l],
                                                                dims[l], dims[l + 1]);
    }

    // ---- 11 GCN layers ----
    const int mmgrid = (N + 63) / 64;

    // order A (FO >= FI): agg (bf16, no epi) -> hb_t; mm epi -> bf16 (MM=2) or fp8 (MM=3)
    #define DO_A(FI, FO, l, MM) { \
        constexpr int jt = FI / 16; constexpr int ng = 256 / jt; \
        agg_kernel<0><<<(N + ng - 1) / ng, 256, 0, stream>>>( \
            h8_main, rowptr, es, nd, B[l], hb_t, nullptr, N, jt, ng); \
        mm_mfma_kernel<FI, FO, MM><<<mmgrid, 256, 0, stream>>>( \
            hb_t, nd, Wp + woff[l], B[l], hb_main, h8_main, N); }

    // order B (FO < FI): mm raw -> h8_t (fp8); agg epi -> h8_main (fp8 only)
    #define DO_B(FI, FO, l) { \
        mm_mfma_kernel<FI, FO, 0><<<mmgrid, 256, 0, stream>>>( \
            hb_main, nd, Wp + woff[l], B[l], nullptr, h8_t, N); \
        constexpr int jt = FO / 16; constexpr int ng = 256 / jt; \
        agg_kernel<2><<<(N + ng - 1) / ng, 256, 0, stream>>>( \
            h8_t, rowptr, es, nd, B[l], nullptr, h8_main, N, jt, ng); }

    DO_A(64, 80, 0, 3)      // next L1 is A: fp8 only (bf16 dead)
    DO_A(80, 160, 1, 2)     // next L2 is B: bf16 only
    DO_B(160, 112, 2)
    DO_A(112, 160, 3, 3)    // next L4 is A: fp8 only
    DO_A(160, 176, 4, 2)    // next L5 is B
    DO_B(176, 96, 5)
    DO_A(96, 144, 6, 2)     // next L7 is B
    DO_B(144, 96, 7)
    DO_A(96, 128, 8, 2)     // next L9 is B
    DO_B(128, 96, 9)
    DO_A(96, 160, 10, 2)    // next is mean: bf16 only

    #undef DO_A
    #undef DO_B

    // ---- mean over nodes -> head ----
    hipMemsetAsync(acc, 0, 160 * sizeof(float), stream);
    mean_kernel<<<256, 320, 0, stream>>>(hb_main, acc, N);
    head_kernel<<<1, 256, 0, stream>>>(acc, Wd1, bd1, Wd2, bd2, out, N);
}